// Round 1
// baseline (1729.629 us; speedup 1.0000x reference)
//
#include <hip/hip_runtime.h>
#include <hip/hip_fp16.h>

#define NN 100000
#define EE 3200000
#define SLOPE 0.2f

#define BKN 128                              // dst-nodes per bucket
constexpr int NBK = (NN + BKN - 1) / BKN;    // 782 buckets
#define CAP 4544                             // mean 4096 + 7 sigma
#define EPB 4096                             // edges per bucket-sort block
constexpr int NBB = (EE + EPB - 1) / EPB;    // 782 sort blocks
constexpr int NBT = (NN + 255) / 256;        // 391 node blocks

// ------------- fat kernel: bucket counting-sort (blocks 0..NBB) + h1 (rest) -----------
// record = {src | (dst&127)<<17, edge_attr}; reservation atomic doubles as bucket count
__global__ void k_fat(const int* __restrict__ src, const int* __restrict__ dst,
                      const float* __restrict__ ea, int* __restrict__ cnt,
                      int2* __restrict__ stage,
                      const int* __restrict__ ids, const float* __restrict__ feat,
                      const float* __restrict__ emb, const float* __restrict__ W,
                      const float* __restrict__ avs, const float* __restrict__ avd,
                      __half* __restrict__ h, float* __restrict__ as_,
                      float* __restrict__ ad_) {
    __shared__ int hst[NBK];
    __shared__ int scl[NBK];
    __shared__ int gdel[NBK];
    __shared__ int aux[256];
    __shared__ int2 rec[EPB];
    __shared__ int addr[EPB];
    int t = threadIdx.x;
    if (blockIdx.x < NBB) {
        // ---------- bucket counting sort ----------
        int base = blockIdx.x * EPB;
        int nedge = min(EPB, EE - base);
        for (int i = t; i < NBK; i += 256) hst[i] = 0;
        __syncthreads();
        int ds[16], ss[16]; float es[16];
#pragma unroll
        for (int j = 0; j < 16; j++) {
            int e = base + j * 256 + t;
            bool v = e < EE;
            ds[j] = v ? dst[e] : -1;
            ss[j] = v ? src[e] : 0;
            es[j] = v ? ea[e] : 0.f;
            if (v) atomicAdd(&hst[ds[j] >> 7], 1);
        }
        __syncthreads();
        int i0 = t * 4;
        int v0 = (i0 + 0 < NBK) ? hst[i0 + 0] : 0;
        int v1 = (i0 + 1 < NBK) ? hst[i0 + 1] : 0;
        int v2 = (i0 + 2 < NBK) ? hst[i0 + 2] : 0;
        int v3 = (i0 + 3 < NBK) ? hst[i0 + 3] : 0;
        int tsum = v0 + v1 + v2 + v3;
        aux[t] = tsum;
        __syncthreads();
        for (int off = 1; off < 256; off <<= 1) {
            int x = (t >= off) ? aux[t - off] : 0;
            __syncthreads();
            aux[t] += x;
            __syncthreads();
        }
        int ex = aux[t] - tsum;
        if (i0 + 0 < NBK) scl[i0 + 0] = ex;
        if (i0 + 1 < NBK) scl[i0 + 1] = ex + v0;
        if (i0 + 2 < NBK) scl[i0 + 2] = ex + v0 + v1;
        if (i0 + 3 < NBK) scl[i0 + 3] = ex + v0 + v1 + v2;
        __syncthreads();
        for (int i = t; i < NBK; i += 256) {
            int hh = hst[i];
            int g = hh ? atomicAdd(&cnt[i], hh) : 0;
            gdel[i] = (g + i * CAP) - scl[i];
        }
        __syncthreads();
#pragma unroll
        for (int j = 0; j < 16; j++) {
            if (ds[j] >= 0) {
                int bk = ds[j] >> 7;
                int pos = atomicAdd(&scl[bk], 1);
                int gpos = pos + gdel[bk];
                rec[pos] = make_int2(ss[j] | ((ds[j] & 127) << 17), __float_as_int(es[j]));
                addr[pos] = (gpos - bk * CAP < CAP) ? gpos : -1;
            }
        }
        __syncthreads();
        for (int i = t; i < nedge; i += 256) {
            int a = addr[i];
            if (a >= 0) stage[a] = rec[i];
        }
    } else {
        // ---------- h1: x=concat(emb,feat); h=x@W1 (stored fp16); as/ad dots fp32 -----
        int n = (blockIdx.x - NBB) * 256 + t;
        if (n >= NN) return;
        float hv[32];
#pragma unroll
        for (int j = 0; j < 32; j++) hv[j] = 0.f;
        int id = ids[n];
        const float4* e4 = (const float4*)(emb + (size_t)id * 16);
#pragma unroll
        for (int k4 = 0; k4 < 4; k4++) {
            float4 xv = e4[k4];
            const float* wr = W + k4 * 4 * 32;
#pragma unroll
            for (int j = 0; j < 32; j++)
                hv[j] += xv.x * wr[j] + xv.y * wr[32 + j] + xv.z * wr[64 + j] + xv.w * wr[96 + j];
        }
        float f = feat[n];
#pragma unroll
        for (int j = 0; j < 32; j++) hv[j] += f * W[16 * 32 + j];
        float s = 0.f, d = 0.f;
#pragma unroll
        for (int j = 0; j < 32; j++) { s += hv[j] * avs[j]; d += hv[j] * avd[j]; }
        as_[n] = s;
        ad_[n] = d;
        __half2 tmp[16];
#pragma unroll
        for (int q = 0; q < 16; q++) tmp[q] = __floats2half2_rn(hv[2 * q], hv[2 * q + 1]);
        uint4* dst4 = (uint4*)(h + (size_t)n * 32);
        const uint4* s4 = (const uint4*)tmp;
#pragma unroll
        for (int q = 0; q < 4; q++) dst4[q] = s4[q];
    }
}

// -------- bucket-parallel GAT aggregation straight from stage (k_build eliminated) ----
// One block per bucket (128 dst nodes). Single pass over the bucket's staged edges:
//   phase A: 1 edge/thread -> ex=exp(leaky(as[src]+ad[dst]+ce*ea)), LDS atomics for
//            exs/esum/deg, record buffered in LDS
//   phase B: 16-lane groups stream h[src] rows (half2/lane, coalesced 64B/row) and
//            ds_add into acc[128][33] (pad -> ~2-way banks, free)
// Epilogue: self-loop (mean edge_attr), normalize; FINAL fuses lin layer, else fuses
// the 32x32 @W2 transform + as2/ad2 dots (k_h2 eliminated, x2 round-trip eliminated).
template <bool FINAL>
__global__ __launch_bounds__(512) void k_agg(
    const int* __restrict__ cnt, const int2* __restrict__ stage,
    const __half* __restrict__ h, const float* __restrict__ as_,
    const float* __restrict__ ad_, const float* __restrict__ We,
    const float* __restrict__ ae, const float* __restrict__ bias,
    const float* __restrict__ W2, const float* __restrict__ avs2,
    const float* __restrict__ avd2, __half* __restrict__ hout,
    float* __restrict__ as2, float* __restrict__ ad2,
    const float* __restrict__ lw, const float* __restrict__ lb,
    float* __restrict__ out) {
    __shared__ float acc[BKN][33];      // padded: bank = (dl+cp)%32
    __shared__ float exs[BKN];
    __shared__ float esum[BKN];
    __shared__ int ldeg[BKN];
    __shared__ float adl[BKN];
    __shared__ int2 ebuf[512];
    __shared__ float w2s[1024];
    int t = threadIdx.x;
    int b = blockIdx.x;
    int nbase = b * BKN;
    int npb = min(BKN, NN - nbase);
    int lane = t & 63;
    int wid = t >> 6;                   // wave 0..7
    int g = lane >> 4;                  // 4 edge-slots per wave
    int cp = (lane & 15) * 2;           // comp pair
    int gid = t >> 4;                   // 32 groups of 16 lanes
    int comp = lane & 31;
    // edge-path constant ce = sum_k We[k]*ae[k]
    float ce = We[comp] * ae[comp];
#pragma unroll
    for (int off = 1; off < 32; off <<= 1) ce += __shfl_xor(ce, off);
    for (int i = t; i < BKN; i += 512) {
        exs[i] = 0.f; esum[i] = 0.f; ldeg[i] = 0;
        adl[i] = (i < npb) ? ad_[nbase + i] : 0.f;
    }
    for (int i = t; i < BKN * 33; i += 512) ((float*)acc)[i] = 0.f;
    if (!FINAL)
        for (int i = t; i < 1024; i += 512) w2s[i] = W2[i];
    __syncthreads();
    int c = min(cnt[b], CAP);
    const int2* ep = stage + (size_t)b * CAP;
    for (int cb = 0; cb < c; cb += 512) {
        // ---- phase A: one edge per thread ----
        int idx = cb + t;
        int2 r = make_int2(0, 0);       // dummy: ex=0 -> harmless adds to acc[0]
        if (idx < c) {
            int2 e = ep[idx];
            int dl = (e.x >> 17) & 127;
            float eav = __int_as_float(e.y);
            float a = as_[e.x & 0x1FFFF] + adl[dl] + ce * eav;
            a = (a >= 0.f) ? a : SLOPE * a;
            float ex = __expf(a);
            atomicAdd(&exs[dl], ex);
            atomicAdd(&esum[dl], eav);
            atomicAdd(&ldeg[dl], 1);
            r = make_int2(e.x, __float_as_int(ex));
        }
        ebuf[t] = r;
        __syncthreads();
        // ---- phase B: wave streams its 64 buffered edges, 16 at a time ----
        const int2* wb = ebuf + wid * 64;
#pragma unroll
        for (int jj = 0; jj < 64; jj += 16) {
            int2 p0 = wb[jj + g];
            int2 p1 = wb[jj + 4 + g];
            int2 p2 = wb[jj + 8 + g];
            int2 p3 = wb[jj + 12 + g];
            float2 v0 = __half22float2(*(const __half2*)(h + ((p0.x & 0x1FFFF) << 5) + cp));
            float2 v1 = __half22float2(*(const __half2*)(h + ((p1.x & 0x1FFFF) << 5) + cp));
            float2 v2 = __half22float2(*(const __half2*)(h + ((p2.x & 0x1FFFF) << 5) + cp));
            float2 v3 = __half22float2(*(const __half2*)(h + ((p3.x & 0x1FFFF) << 5) + cp));
            float w0 = __int_as_float(p0.y), w1 = __int_as_float(p1.y);
            float w2 = __int_as_float(p2.y), w3 = __int_as_float(p3.y);
            int d0 = (p0.x >> 17) & 127, d1 = (p1.x >> 17) & 127;
            int d2 = (p2.x >> 17) & 127, d3 = (p3.x >> 17) & 127;
            atomicAdd(&acc[d0][cp], w0 * v0.x);
            atomicAdd(&acc[d0][cp + 1], w0 * v0.y);
            atomicAdd(&acc[d1][cp], w1 * v1.x);
            atomicAdd(&acc[d1][cp + 1], w1 * v1.y);
            atomicAdd(&acc[d2][cp], w2 * v2.x);
            atomicAdd(&acc[d2][cp + 1], w2 * v2.y);
            atomicAdd(&acc[d3][cp], w3 * v3.x);
            atomicAdd(&acc[d3][cp + 1], w3 * v3.y);
        }
        __syncthreads();
    }
    // ---- epilogue: self-loop + normalize; 16-lane group per node ----
    for (int n = gid; n < npb; n += 32) {
        int gn = nbase + n;
        float mean = esum[n] / fmaxf((float)ldeg[n], 1.0f);
        float a = as_[gn] + adl[n] + ce * mean;
        a = (a >= 0.f) ? a : SLOPE * a;
        float ex = __expf(a);
        float2 hh = __half22float2(*(const __half2*)(h + ((size_t)gn << 5) + cp));
        float sx = acc[n][cp] + ex * hh.x;
        float sy = acc[n][cp + 1] + ex * hh.y;
        float inv = 1.0f / (exs[n] + ex + 1e-16f);
        float ox = sx * inv + bias[cp];
        float oy = sy * inv + bias[cp + 1];
        if (FINAL) {
            float y = ox * lw[cp] + oy * lw[cp + 1];        // fused final linear 32->1
#pragma unroll
            for (int off = 1; off < 16; off <<= 1) y += __shfl_xor(y, off);
            if ((t & 15) == 0) out[gn] = y + lb[0];
        } else {
            ox = fmaxf(ox, 0.f);
            oy = fmaxf(oy, 0.f);
            acc[n][cp] = ox;                // stash relu'd x row (wave-lockstep safe)
            acc[n][cp + 1] = oy;
            float hx = 0.f, hy = 0.f;       // fused h2 = x @ W2
#pragma unroll
            for (int k = 0; k < 32; k += 2) {
                float xk = acc[n][k], xk1 = acc[n][k + 1];
                float2 wk = *(const float2*)(w2s + k * 32 + cp);
                float2 wk1 = *(const float2*)(w2s + (k + 1) * 32 + cp);
                hx += xk * wk.x + xk1 * wk1.x;
                hy += xk * wk.y + xk1 * wk1.y;
            }
            float ps = hx * avs2[cp] + hy * avs2[cp + 1];
            float pd = hx * avd2[cp] + hy * avd2[cp + 1];
#pragma unroll
            for (int off = 1; off < 16; off <<= 1) {
                ps += __shfl_xor(ps, off);
                pd += __shfl_xor(pd, off);
            }
            if ((t & 15) == 0) { as2[gn] = ps; ad2[gn] = pd; }
            *(__half2*)(hout + ((size_t)gn << 5) + cp) = __floats2half2_rn(hx, hy);
        }
    }
}

// ---------------- launch ----------------

extern "C" void kernel_launch(void* const* d_in, const int* in_sizes, int n_in,
                              void* d_out, int out_size, void* d_ws, size_t ws_size,
                              hipStream_t stream) {
    const int* x_ids = (const int*)d_in[0];
    const float* x_feat = (const float*)d_in[1];
    const int* src = (const int*)d_in[2];
    const int* dst = (const int*)d_in[3];
    const float* eattr = (const float*)d_in[4];
    const float* emb = (const float*)d_in[5];
    const float* W1 = (const float*)d_in[6];
    const float* a_s1 = (const float*)d_in[7];
    const float* a_d1 = (const float*)d_in[8];
    const float* We1 = (const float*)d_in[9];
    const float* a_e1 = (const float*)d_in[10];
    const float* b1 = (const float*)d_in[11];
    const float* W2 = (const float*)d_in[12];
    const float* a_s2 = (const float*)d_in[13];
    const float* a_d2 = (const float*)d_in[14];
    const float* We2 = (const float*)d_in[15];
    const float* a_e2 = (const float*)d_in[16];
    const float* b2 = (const float*)d_in[17];
    const float* lin_w = (const float*)d_in[18];
    const float* lin_b = (const float*)d_in[19];

    char* p = (char*)d_ws;
    auto alloc = [&](size_t bytes) {
        void* r = (void*)p;
        p += (bytes + 255) & ~(size_t)255;
        return r;
    };
    int* cnt = (int*)alloc(NBK * 4);
    float* asb1 = (float*)alloc(NN * 4);
    float* adb1 = (float*)alloc(NN * 4);
    float* asb2 = (float*)alloc(NN * 4);
    float* adb2 = (float*)alloc(NN * 4);
    __half* h1 = (__half*)alloc((size_t)NN * 32 * 2);    // 6.4 MB fp16
    __half* h2 = (__half*)alloc((size_t)NN * 32 * 2);    // 6.4 MB fp16
    int2* stage = (int2*)alloc((size_t)NBK * CAP * 8);   // 28.4 MB, lives through both layers
    (void)ws_size; (void)in_sizes; (void)n_in; (void)out_size;

    hipMemsetAsync(cnt, 0, NBK * 4, stream);

    k_fat<<<NBB + NBT, 256, 0, stream>>>(src, dst, eattr, cnt, stage,
                                         x_ids, x_feat, emb, W1, a_s1, a_d1,
                                         h1, asb1, adb1);
    k_agg<false><<<NBK, 512, 0, stream>>>(cnt, stage, h1, asb1, adb1,
                                          We1, a_e1, b1,
                                          W2, a_s2, a_d2, h2, asb2, adb2,
                                          nullptr, nullptr, nullptr);
    k_agg<true><<<NBK, 512, 0, stream>>>(cnt, stage, h2, asb2, adb2,
                                         We2, a_e2, b2,
                                         nullptr, nullptr, nullptr,
                                         nullptr, nullptr, nullptr,
                                         lin_w, lin_b, (float*)d_out);
}

// Round 2
// 396.706 us; speedup vs baseline: 4.3600x; 4.3600x over previous
//
#include <hip/hip_runtime.h>
#include <hip/hip_fp16.h>

#define NN 100000
#define EE 3200000
#define SLOPE 0.2f

#define BKN 128                              // dst-nodes per bucket
constexpr int NBK = (NN + BKN - 1) / BKN;    // 782 buckets
#define CAP 4544                             // mean 4096 + 7 sigma
#define CSLOT (CAP + BKN)                    // LDS edge buffer incl. self-loop slots
#define EPB 4096                             // edges per bucket-sort block
constexpr int NBB = (EE + EPB - 1) / EPB;    // 782 sort blocks
constexpr int NBT = (NN + 255) / 256;        // 391 node blocks

// ------------- fat kernel: bucket counting-sort (blocks 0..NBB) + h1 (rest) -----------
// record = {src | (dst&127)<<17, edge_attr}; reservation atomic doubles as bucket count
__global__ void k_fat(const int* __restrict__ src, const int* __restrict__ dst,
                      const float* __restrict__ ea, int* __restrict__ cnt,
                      int2* __restrict__ stage,
                      const int* __restrict__ ids, const float* __restrict__ feat,
                      const float* __restrict__ emb, const float* __restrict__ W,
                      const float* __restrict__ avs, const float* __restrict__ avd,
                      __half* __restrict__ h, float* __restrict__ as_,
                      float* __restrict__ ad_) {
    __shared__ int hst[NBK];
    __shared__ int scl[NBK];
    __shared__ int gdel[NBK];
    __shared__ int aux[256];
    __shared__ int2 rec[EPB];
    __shared__ int addr[EPB];
    int t = threadIdx.x;
    if (blockIdx.x < NBB) {
        // ---------- bucket counting sort ----------
        int base = blockIdx.x * EPB;
        int nedge = min(EPB, EE - base);
        for (int i = t; i < NBK; i += 256) hst[i] = 0;
        __syncthreads();
        int ds[16], ss[16]; float es[16];
#pragma unroll
        for (int j = 0; j < 16; j++) {
            int e = base + j * 256 + t;
            bool v = e < EE;
            ds[j] = v ? dst[e] : -1;
            ss[j] = v ? src[e] : 0;
            es[j] = v ? ea[e] : 0.f;
            if (v) atomicAdd(&hst[ds[j] >> 7], 1);
        }
        __syncthreads();
        int i0 = t * 4;
        int v0 = (i0 + 0 < NBK) ? hst[i0 + 0] : 0;
        int v1 = (i0 + 1 < NBK) ? hst[i0 + 1] : 0;
        int v2 = (i0 + 2 < NBK) ? hst[i0 + 2] : 0;
        int v3 = (i0 + 3 < NBK) ? hst[i0 + 3] : 0;
        int tsum = v0 + v1 + v2 + v3;
        aux[t] = tsum;
        __syncthreads();
        for (int off = 1; off < 256; off <<= 1) {
            int x = (t >= off) ? aux[t - off] : 0;
            __syncthreads();
            aux[t] += x;
            __syncthreads();
        }
        int ex = aux[t] - tsum;
        if (i0 + 0 < NBK) scl[i0 + 0] = ex;
        if (i0 + 1 < NBK) scl[i0 + 1] = ex + v0;
        if (i0 + 2 < NBK) scl[i0 + 2] = ex + v0 + v1;
        if (i0 + 3 < NBK) scl[i0 + 3] = ex + v0 + v1 + v2;
        __syncthreads();
        for (int i = t; i < NBK; i += 256) {
            int hh = hst[i];
            int g = hh ? atomicAdd(&cnt[i], hh) : 0;
            gdel[i] = (g + i * CAP) - scl[i];
        }
        __syncthreads();
#pragma unroll
        for (int j = 0; j < 16; j++) {
            if (ds[j] >= 0) {
                int bk = ds[j] >> 7;
                int pos = atomicAdd(&scl[bk], 1);
                int gpos = pos + gdel[bk];
                rec[pos] = make_int2(ss[j] | ((ds[j] & 127) << 17), __float_as_int(es[j]));
                addr[pos] = (gpos - bk * CAP < CAP) ? gpos : -1;
            }
        }
        __syncthreads();
        for (int i = t; i < nedge; i += 256) {
            int a = addr[i];
            if (a >= 0) stage[a] = rec[i];
        }
    } else {
        // ---------- h1: x=concat(emb,feat); h=x@W1 (stored fp16); as/ad dots fp32 -----
        int n = (blockIdx.x - NBB) * 256 + t;
        if (n >= NN) return;
        float hv[32];
#pragma unroll
        for (int j = 0; j < 32; j++) hv[j] = 0.f;
        int id = ids[n];
        const float4* e4 = (const float4*)(emb + (size_t)id * 16);
#pragma unroll
        for (int k4 = 0; k4 < 4; k4++) {
            float4 xv = e4[k4];
            const float* wr = W + k4 * 4 * 32;
#pragma unroll
            for (int j = 0; j < 32; j++)
                hv[j] += xv.x * wr[j] + xv.y * wr[32 + j] + xv.z * wr[64 + j] + xv.w * wr[96 + j];
        }
        float f = feat[n];
#pragma unroll
        for (int j = 0; j < 32; j++) hv[j] += f * W[16 * 32 + j];
        float s = 0.f, d = 0.f;
#pragma unroll
        for (int j = 0; j < 32; j++) { s += hv[j] * avs[j]; d += hv[j] * avd[j]; }
        as_[n] = s;
        ad_[n] = d;
        __half2 tmp[16];
#pragma unroll
        for (int q = 0; q < 16; q++) tmp[q] = __floats2half2_rn(hv[2 * q], hv[2 * q + 1]);
        uint4* dst4 = (uint4*)(h + (size_t)n * 32);
        const uint4* s4 = (const uint4*)tmp;
#pragma unroll
        for (int q = 0; q < 4; q++) dst4[q] = s4[q];
    }
}

// -------- fused GAT: in-LDS counting sort of the bucket, then wave-per-node ----------
// One block (512 thr, 8 waves) per bucket. Sort phase = k_build's proven code but
// scattering into LDS ebuf (csr array + k_build kernel eliminated); self-loop edge
// (mean attr) appended per node. Agg phase = the proven register-accumulator
// wave-per-node loop (NO LDS atomics) reading edges from LDS. Epilogue: FINAL fuses
// the 32->1 linear; else fuses h2 = relu(out)@W2 + as2/ad2 (k_h2 + x2 eliminated).
template <bool FINAL>
__global__ __launch_bounds__(512, 6) void k_agg(
    const int* __restrict__ cnt, const int2* __restrict__ stage,
    const __half* __restrict__ h, const float* __restrict__ as_,
    const float* __restrict__ ad_, const float* __restrict__ We,
    const float* __restrict__ ae, const float* __restrict__ bias,
    const float* __restrict__ W2, const float* __restrict__ avs2,
    const float* __restrict__ avd2, __half* __restrict__ hout,
    float* __restrict__ as2, float* __restrict__ ad2,
    const float* __restrict__ lw, const float* __restrict__ lb,
    float* __restrict__ out) {
    __shared__ int2 ebuf[CSLOT];        // 37.4 KB node-sorted edges
    __shared__ int2 xb[8][64];          // per-wave phase buffer
    __shared__ float w2s[1024];         // W2 (layer-1 variant only)
    __shared__ float xrow[8][32];       // per-wave relu'd output row
    __shared__ int ldeg[BKN];
    __shared__ float esum[BKN];
    __shared__ int starts[BKN];
    __shared__ int lcur[BKN];
    __shared__ int cnts[BKN];
    int t = threadIdx.x;
    int b = blockIdx.x;
    int nbase = b * BKN;
    int npb = min(BKN, NN - nbase);
    int lane = t & 63;
    int wid = t >> 6;                   // wave 0..7
    int g = lane >> 4;                  // 4 edge-slots
    int cp = (lane & 15) * 2;           // comp pair
    int comp = lane & 31;
    // edge-path constant ce = sum_k We[k]*ae[k]
    float ce = We[comp] * ae[comp];
#pragma unroll
    for (int off = 1; off < 32; off <<= 1) ce += __shfl_xor(ce, off);

    // ---------------- in-LDS counting sort ----------------
    for (int i = t; i < BKN; i += 512) { ldeg[i] = 0; esum[i] = 0.f; }
    if (!FINAL)
        for (int i = t; i < 1024; i += 512) w2s[i] = W2[i];
    __syncthreads();
    int c = min(cnt[b], CAP);
    const int2* ep = stage + (size_t)b * CAP;
    for (int i = t; i < c; i += 512) {          // pass 1: count (stage -> L2-hot)
        int2 e = ep[i];
        int n = (e.x >> 17) & 127;
        atomicAdd(&ldeg[n], 1);
        atomicAdd(&esum[n], __int_as_float(e.y));
    }
    __syncthreads();
    int v = (t < npb) ? ldeg[t] + 1 : 0;        // +1 self-loop slot
    if (t < BKN) starts[t] = v;
    __syncthreads();
    for (int off = 1; off < BKN; off <<= 1) {
        int x = (t >= off && t < BKN) ? starts[t - off] : 0;
        __syncthreads();
        if (t < BKN) starts[t] += x;
        __syncthreads();
    }
    if (t < BKN) {
        int st = starts[t] - v;                 // exclusive scan
        lcur[t] = st;
        cnts[t] = v;
        starts[t] = st;
    }
    __syncthreads();
    for (int i = t; i < c; i += 512) {          // pass 2: scatter into LDS
        int2 e = ep[i];
        int n = (e.x >> 17) & 127;
        int pos = atomicAdd(&lcur[n], 1);
        ebuf[pos] = make_int2(e.x & 0x1FFFF, e.y);
    }
    __syncthreads();
    if (t < npb) {                              // self-loop edge, attr = mean
        float mean = esum[t] / fmaxf((float)ldeg[t], 1.0f);
        ebuf[lcur[t]] = make_int2(nbase + t, __float_as_int(mean));
    }
    __syncthreads();

    // ---------------- wave-per-node aggregation (register accumulators) -------------
    for (int i = 0; i < 16; i++) {
        int n = wid * 16 + i;                   // wave-uniform
        if (n >= npb) break;
        int gn = nbase + n;
        int base2 = starts[n];
        int cn = cnts[n];                       // >= 1 (self-loop)
        float adn = ad_[gn];
        float2 acc0 = {0.f, 0.f}, acc1 = {0.f, 0.f}, acc2 = {0.f, 0.f}, acc3 = {0.f, 0.f};
        float exs = 0.f;
        for (int cb = 0; cb < cn; cb += 64) {
            // phase A: one edge per lane, exp once
            int idx = cb + lane;
            bool val = idx < cn;
            int2 e = ebuf[base2 + (val ? idx : 0)];
            float a = as_[e.x] + adn + ce * __int_as_float(e.y);
            a = (a >= 0.f) ? a : SLOPE * a;
            float ex = val ? __expf(a) : 0.f;
            exs += ex;
            xb[wid][lane] = make_int2(e.x << 5, __float_as_int(ex));
            // phase B: 16 edges/iter across 4 slots, 4 half2 h-loads in flight
            int m = min(cn - cb, 64);
            for (int j = 0; j < m; j += 16) {
                int2 p0 = xb[wid][j + g];
                int2 p1 = xb[wid][j + 4 + g];
                int2 p2 = xb[wid][j + 8 + g];
                int2 p3 = xb[wid][j + 12 + g];
                float2 h0 = __half22float2(*(const __half2*)(h + p0.x + cp));
                float2 h1 = __half22float2(*(const __half2*)(h + p1.x + cp));
                float2 h2 = __half22float2(*(const __half2*)(h + p2.x + cp));
                float2 h3 = __half22float2(*(const __half2*)(h + p3.x + cp));
                float w0 = __int_as_float(p0.y), w1 = __int_as_float(p1.y);
                float w2 = __int_as_float(p2.y), w3 = __int_as_float(p3.y);
                acc0.x += w0 * h0.x; acc0.y += w0 * h0.y;
                acc1.x += w1 * h1.x; acc1.y += w1 * h1.y;
                acc2.x += w2 * h2.x; acc2.y += w2 * h2.y;
                acc3.x += w3 * h3.x; acc3.y += w3 * h3.y;
            }
        }
        float2 acc;
        acc.x = (acc0.x + acc1.x) + (acc2.x + acc3.x);
        acc.y = (acc0.y + acc1.y) + (acc2.y + acc3.y);
        acc.x += __shfl_xor(acc.x, 16); acc.y += __shfl_xor(acc.y, 16);
        acc.x += __shfl_xor(acc.x, 32); acc.y += __shfl_xor(acc.y, 32);
#pragma unroll
        for (int off = 1; off < 64; off <<= 1) exs += __shfl_xor(exs, off);
        float inv = 1.0f / (exs + 1e-16f);
        float ox = acc.x * inv + bias[cp];
        float oy = acc.y * inv + bias[cp + 1];
        if (FINAL) {
            float y = ox * lw[cp] + oy * lw[cp + 1];     // fused final linear 32 -> 1
#pragma unroll
            for (int off = 1; off < 16; off <<= 1) y += __shfl_xor(y, off);
            if (lane == 0) out[gn] = y + lb[0];
        } else {
            ox = fmaxf(ox, 0.f);
            oy = fmaxf(oy, 0.f);
            if (lane < 16) { xrow[wid][cp] = ox; xrow[wid][cp + 1] = oy; }
            // fused h2 = relu(x) @ W2 (same-wave LDS write->read, lockstep safe)
            float hx = 0.f, hy = 0.f;
#pragma unroll
            for (int k = 0; k < 32; k++) {
                float xk = xrow[wid][k];
                hx += xk * w2s[k * 32 + cp];
                hy += xk * w2s[k * 32 + cp + 1];
            }
            float ps = hx * avs2[cp] + hy * avs2[cp + 1];
            float pd = hx * avd2[cp] + hy * avd2[cp + 1];
#pragma unroll
            for (int off = 1; off < 16; off <<= 1) {
                ps += __shfl_xor(ps, off);
                pd += __shfl_xor(pd, off);
            }
            if (lane == 0) { as2[gn] = ps; ad2[gn] = pd; }
            if (lane < 16)
                *(__half2*)(hout + ((size_t)gn << 5) + cp) = __floats2half2_rn(hx, hy);
        }
    }
}

// ---------------- launch ----------------

extern "C" void kernel_launch(void* const* d_in, const int* in_sizes, int n_in,
                              void* d_out, int out_size, void* d_ws, size_t ws_size,
                              hipStream_t stream) {
    const int* x_ids = (const int*)d_in[0];
    const float* x_feat = (const float*)d_in[1];
    const int* src = (const int*)d_in[2];
    const int* dst = (const int*)d_in[3];
    const float* eattr = (const float*)d_in[4];
    const float* emb = (const float*)d_in[5];
    const float* W1 = (const float*)d_in[6];
    const float* a_s1 = (const float*)d_in[7];
    const float* a_d1 = (const float*)d_in[8];
    const float* We1 = (const float*)d_in[9];
    const float* a_e1 = (const float*)d_in[10];
    const float* b1 = (const float*)d_in[11];
    const float* W2 = (const float*)d_in[12];
    const float* a_s2 = (const float*)d_in[13];
    const float* a_d2 = (const float*)d_in[14];
    const float* We2 = (const float*)d_in[15];
    const float* a_e2 = (const float*)d_in[16];
    const float* b2 = (const float*)d_in[17];
    const float* lin_w = (const float*)d_in[18];
    const float* lin_b = (const float*)d_in[19];

    char* p = (char*)d_ws;
    auto alloc = [&](size_t bytes) {
        void* r = (void*)p;
        p += (bytes + 255) & ~(size_t)255;
        return r;
    };
    int* cnt = (int*)alloc(NBK * 4);
    float* asb1 = (float*)alloc(NN * 4);
    float* adb1 = (float*)alloc(NN * 4);
    float* asb2 = (float*)alloc(NN * 4);
    float* adb2 = (float*)alloc(NN * 4);
    __half* h1 = (__half*)alloc((size_t)NN * 32 * 2);    // 6.4 MB fp16
    __half* h2 = (__half*)alloc((size_t)NN * 32 * 2);    // 6.4 MB fp16
    int2* stage = (int2*)alloc((size_t)NBK * CAP * 8);   // 28.4 MB, lives thru both layers
    (void)ws_size; (void)in_sizes; (void)n_in; (void)out_size;

    hipMemsetAsync(cnt, 0, NBK * 4, stream);

    k_fat<<<NBB + NBT, 256, 0, stream>>>(src, dst, eattr, cnt, stage,
                                         x_ids, x_feat, emb, W1, a_s1, a_d1,
                                         h1, asb1, adb1);
    k_agg<false><<<NBK, 512, 0, stream>>>(cnt, stage, h1, asb1, adb1,
                                          We1, a_e1, b1,
                                          W2, a_s2, a_d2, h2, asb2, adb2,
                                          nullptr, nullptr, nullptr);
    k_agg<true><<<NBK, 512, 0, stream>>>(cnt, stage, h2, asb2, adb2,
                                         We2, a_e2, b2,
                                         nullptr, nullptr, nullptr,
                                         nullptr, nullptr, nullptr,
                                         lin_w, lin_b, (float*)d_out);
}

// Round 3
// 349.255 us; speedup vs baseline: 4.9523x; 1.1359x over previous
//
#include <hip/hip_runtime.h>
#include <hip/hip_fp16.h>

#define NN 100000
#define EE 3200000
#define SLOPE 0.2f

#define BKN 128                              // dst-nodes per coarse bucket
constexpr int NBK = (NN + BKN - 1) / BKN;    // 782 buckets
#define CAP 4544                             // coarse bucket cap: mean 4096 + 7 sigma
#define EPB 4096                             // edges per bucket-sort block
constexpr int NBB = (EE + EPB - 1) / EPB;    // 782 sort blocks
constexpr int NBT = (NN + 255) / 256;        // 391 node blocks
#define SUBN 1344                            // LDS edge cap per 32-node sub-bucket
                                             //   (mean 1024+32, +9 sigma slack)

// ------------- fat kernel: bucket counting-sort (blocks 0..NBB) + h1 (rest) -----------
// record = {src | (dst&127)<<17, edge_attr}; reservation atomic doubles as bucket count
__global__ void k_fat(const int* __restrict__ src, const int* __restrict__ dst,
                      const float* __restrict__ ea, int* __restrict__ cnt,
                      int2* __restrict__ stage,
                      const int* __restrict__ ids, const float* __restrict__ feat,
                      const float* __restrict__ emb, const float* __restrict__ W,
                      const float* __restrict__ avs, const float* __restrict__ avd,
                      __half* __restrict__ h, float* __restrict__ as_,
                      float* __restrict__ ad_) {
    __shared__ int hst[NBK];
    __shared__ int scl[NBK];
    __shared__ int gdel[NBK];
    __shared__ int aux[256];
    __shared__ int2 rec[EPB];
    __shared__ int addr[EPB];
    int t = threadIdx.x;
    if (blockIdx.x < NBB) {
        // ---------- bucket counting sort ----------
        int base = blockIdx.x * EPB;
        int nedge = min(EPB, EE - base);
        for (int i = t; i < NBK; i += 256) hst[i] = 0;
        __syncthreads();
        int ds[16], ss[16]; float es[16];
#pragma unroll
        for (int j = 0; j < 16; j++) {
            int e = base + j * 256 + t;
            bool v = e < EE;
            ds[j] = v ? dst[e] : -1;
            ss[j] = v ? src[e] : 0;
            es[j] = v ? ea[e] : 0.f;
            if (v) atomicAdd(&hst[ds[j] >> 7], 1);
        }
        __syncthreads();
        int i0 = t * 4;
        int v0 = (i0 + 0 < NBK) ? hst[i0 + 0] : 0;
        int v1 = (i0 + 1 < NBK) ? hst[i0 + 1] : 0;
        int v2 = (i0 + 2 < NBK) ? hst[i0 + 2] : 0;
        int v3 = (i0 + 3 < NBK) ? hst[i0 + 3] : 0;
        int tsum = v0 + v1 + v2 + v3;
        aux[t] = tsum;
        __syncthreads();
        for (int off = 1; off < 256; off <<= 1) {
            int x = (t >= off) ? aux[t - off] : 0;
            __syncthreads();
            aux[t] += x;
            __syncthreads();
        }
        int ex = aux[t] - tsum;
        if (i0 + 0 < NBK) scl[i0 + 0] = ex;
        if (i0 + 1 < NBK) scl[i0 + 1] = ex + v0;
        if (i0 + 2 < NBK) scl[i0 + 2] = ex + v0 + v1;
        if (i0 + 3 < NBK) scl[i0 + 3] = ex + v0 + v1 + v2;
        __syncthreads();
        for (int i = t; i < NBK; i += 256) {
            int hh = hst[i];
            int g = hh ? atomicAdd(&cnt[i], hh) : 0;
            gdel[i] = (g + i * CAP) - scl[i];
        }
        __syncthreads();
#pragma unroll
        for (int j = 0; j < 16; j++) {
            if (ds[j] >= 0) {
                int bk = ds[j] >> 7;
                int pos = atomicAdd(&scl[bk], 1);
                int gpos = pos + gdel[bk];
                rec[pos] = make_int2(ss[j] | ((ds[j] & 127) << 17), __float_as_int(es[j]));
                addr[pos] = (gpos - bk * CAP < CAP) ? gpos : -1;
            }
        }
        __syncthreads();
        for (int i = t; i < nedge; i += 256) {
            int a = addr[i];
            if (a >= 0) stage[a] = rec[i];
        }
    } else {
        // ---------- h1: x=concat(emb,feat); h=x@W1 (stored fp16); as/ad dots fp32 -----
        int n = (blockIdx.x - NBB) * 256 + t;
        if (n >= NN) return;
        float hv[32];
#pragma unroll
        for (int j = 0; j < 32; j++) hv[j] = 0.f;
        int id = ids[n];
        const float4* e4 = (const float4*)(emb + (size_t)id * 16);
#pragma unroll
        for (int k4 = 0; k4 < 4; k4++) {
            float4 xv = e4[k4];
            const float* wr = W + k4 * 4 * 32;
#pragma unroll
            for (int j = 0; j < 32; j++)
                hv[j] += xv.x * wr[j] + xv.y * wr[32 + j] + xv.z * wr[64 + j] + xv.w * wr[96 + j];
        }
        float f = feat[n];
#pragma unroll
        for (int j = 0; j < 32; j++) hv[j] += f * W[16 * 32 + j];
        float s = 0.f, d = 0.f;
#pragma unroll
        for (int j = 0; j < 32; j++) { s += hv[j] * avs[j]; d += hv[j] * avd[j]; }
        as_[n] = s;
        ad_[n] = d;
        __half2 tmp[16];
#pragma unroll
        for (int q = 0; q < 16; q++) tmp[q] = __floats2half2_rn(hv[2 * q], hv[2 * q + 1]);
        uint4* dst4 = (uint4*)(h + (size_t)n * 32);
        const uint4* s4 = (const uint4*)tmp;
#pragma unroll
        for (int q = 0; q < 4; q++) dst4[q] = s4[q];
    }
}

// -------- fused GAT: sub-bucket (32 nodes) in-LDS sort + wave-per-node agg -----------
// 4 blocks (256 thr, 4 waves) per coarse bucket; block q filters the bucket's stage
// region for its 32 nodes (region is L2-hot, siblings share it), 1-wave shfl scan,
// scatter into 10.5 KB LDS ebuf, append self-loop (mean attr). Agg = proven R0
// register-accumulator wave-per-node loop (8 nodes/wave) reading edges from LDS.
// FINAL fuses 32->1 linear; else fuses h2 = relu(out)@W2 + as2/ad2 dots.
// csr/offs2/k_build/k_h2 all eliminated; layer 2 simply redoes the cheap LDS sort.
template <bool FINAL>
__global__ __launch_bounds__(256, 6) void k_agg(
    const int* __restrict__ cnt, const int2* __restrict__ stage,
    const __half* __restrict__ h, const float* __restrict__ as_,
    const float* __restrict__ ad_, const float* __restrict__ We,
    const float* __restrict__ ae, const float* __restrict__ bias,
    const float* __restrict__ W2, const float* __restrict__ avs2,
    const float* __restrict__ avd2, __half* __restrict__ hout,
    float* __restrict__ as2, float* __restrict__ ad2,
    const float* __restrict__ lw, const float* __restrict__ lb,
    float* __restrict__ out) {
    __shared__ int2 ebuf[SUBN];         // 10.5 KB node-sorted edges (32 nodes)
    __shared__ int2 xb[4][64];          // per-wave phase buffer
    __shared__ float w2s[1024];         // W2 (layer-1 variant only)
    __shared__ float xrow[4][32];       // per-wave relu'd output row
    __shared__ int ldeg[32];
    __shared__ float esum[32];
    __shared__ int starts[32];
    __shared__ int lcur[32];
    __shared__ int cnts[32];
    __shared__ float means[32];
    int t = threadIdx.x;
    int b2 = blockIdx.x;
    int b = b2 >> 2, q = b2 & 3;
    int nbase = b * BKN + q * 32;
    int npb = min(32, NN - nbase);
    if (npb <= 0) return;               // tail sub-buckets past NN
    int lane = t & 63;
    int wid = t >> 6;                   // wave 0..3
    int g = lane >> 4;                  // 4 edge-slots
    int cp = (lane & 15) * 2;           // comp pair
    int comp = lane & 31;
    // edge-path constant ce = sum_k We[k]*ae[k]
    float ce = We[comp] * ae[comp];
#pragma unroll
    for (int off = 1; off < 32; off <<= 1) ce += __shfl_xor(ce, off);

    // ---------------- filter + count ----------------
    if (t < 32) { ldeg[t] = 0; esum[t] = 0.f; }
    if (!FINAL)
        for (int i = t; i < 1024; i += 256) w2s[i] = W2[i];
    __syncthreads();
    int c = min(cnt[b], CAP);
    const int2* ep = stage + (size_t)b * CAP;
    for (int i = t; i < c; i += 256) {
        int2 e = ep[i];
        int dl = (e.x >> 17) & 127;
        if ((dl >> 5) == q) {
            atomicAdd(&ldeg[dl & 31], 1);
            atomicAdd(&esum[dl & 31], __int_as_float(e.y));
        }
    }
    __syncthreads();
    // ---------------- 1-wave shfl scan over 32 nodes ----------------
    if (t < 64) {
        int l = lane;
        int dv = (l < npb) ? ldeg[l] + 1 : 0;       // +1 self-loop slot
        int v = dv;
#pragma unroll
        for (int off = 1; off < 32; off <<= 1) {
            int x = __shfl_up(v, off);
            if (lane >= off) v += x;
        }
        if (l < 32) {
            int st = v - dv;                        // exclusive
            starts[l] = st;
            lcur[l] = st;
            cnts[l] = dv;
            means[l] = esum[l] / fmaxf((float)ldeg[l], 1.0f);
        }
    }
    __syncthreads();
    // ---------------- scatter into LDS ----------------
    for (int i = t; i < c; i += 256) {
        int2 e = ep[i];
        int dl = (e.x >> 17) & 127;
        if ((dl >> 5) == q) {
            int pos = atomicAdd(&lcur[dl & 31], 1);
            if (pos < SUBN) ebuf[pos] = make_int2(e.x & 0x1FFFF, e.y);
        }
    }
    __syncthreads();
    if (t < npb) {                                  // self-loop edge, attr = mean
        int p = lcur[t];
        if (p < SUBN) ebuf[p] = make_int2(nbase + t, __float_as_int(means[t]));
    }
    __syncthreads();

    // ---------------- wave-per-node aggregation (register accumulators) -------------
    for (int i2 = 0; i2 < 8; i2++) {
        int n = wid * 8 + i2;                       // wave-uniform
        if (n >= npb) break;
        int gn = nbase + n;
        int base2 = starts[n];
        int cn = cnts[n];
        if (base2 >= SUBN) cn = 0;
        else if (cn > SUBN - base2) cn = SUBN - base2;   // overflow guard (never hit)
        float adn = ad_[gn];
        float2 acc0 = {0.f, 0.f}, acc1 = {0.f, 0.f}, acc2 = {0.f, 0.f}, acc3 = {0.f, 0.f};
        float exs = 0.f;
        for (int cb = 0; cb < cn; cb += 64) {
            // phase A: one edge per lane, exp once
            int idx = cb + lane;
            bool val = idx < cn;
            int2 e = ebuf[base2 + (val ? idx : 0)];
            float a = as_[e.x] + adn + ce * __int_as_float(e.y);
            a = (a >= 0.f) ? a : SLOPE * a;
            float ex = val ? __expf(a) : 0.f;
            exs += ex;
            xb[wid][lane] = make_int2(e.x << 5, __float_as_int(ex));
            // phase B: 16 edges/iter across 4 slots, 4 half2 h-loads in flight
            int m = min(cn - cb, 64);
            for (int j = 0; j < m; j += 16) {
                int2 p0 = xb[wid][j + g];
                int2 p1 = xb[wid][j + 4 + g];
                int2 p2 = xb[wid][j + 8 + g];
                int2 p3 = xb[wid][j + 12 + g];
                float2 h0 = __half22float2(*(const __half2*)(h + p0.x + cp));
                float2 h1 = __half22float2(*(const __half2*)(h + p1.x + cp));
                float2 h2 = __half22float2(*(const __half2*)(h + p2.x + cp));
                float2 h3 = __half22float2(*(const __half2*)(h + p3.x + cp));
                float w0 = __int_as_float(p0.y), w1 = __int_as_float(p1.y);
                float w2 = __int_as_float(p2.y), w3 = __int_as_float(p3.y);
                acc0.x += w0 * h0.x; acc0.y += w0 * h0.y;
                acc1.x += w1 * h1.x; acc1.y += w1 * h1.y;
                acc2.x += w2 * h2.x; acc2.y += w2 * h2.y;
                acc3.x += w3 * h3.x; acc3.y += w3 * h3.y;
            }
        }
        float2 acc;
        acc.x = (acc0.x + acc1.x) + (acc2.x + acc3.x);
        acc.y = (acc0.y + acc1.y) + (acc2.y + acc3.y);
        acc.x += __shfl_xor(acc.x, 16); acc.y += __shfl_xor(acc.y, 16);
        acc.x += __shfl_xor(acc.x, 32); acc.y += __shfl_xor(acc.y, 32);
#pragma unroll
        for (int off = 1; off < 64; off <<= 1) exs += __shfl_xor(exs, off);
        float inv = 1.0f / (exs + 1e-16f);
        float ox = acc.x * inv + bias[cp];
        float oy = acc.y * inv + bias[cp + 1];
        if (FINAL) {
            float y = ox * lw[cp] + oy * lw[cp + 1];     // fused final linear 32 -> 1
#pragma unroll
            for (int off = 1; off < 16; off <<= 1) y += __shfl_xor(y, off);
            if (lane == 0) out[gn] = y + lb[0];
        } else {
            ox = fmaxf(ox, 0.f);
            oy = fmaxf(oy, 0.f);
            if (lane < 16) { xrow[wid][cp] = ox; xrow[wid][cp + 1] = oy; }
            // fused h2 = relu(x) @ W2 (same-wave LDS write->read, lockstep safe)
            float hx = 0.f, hy = 0.f;
#pragma unroll
            for (int k = 0; k < 32; k++) {
                float xk = xrow[wid][k];
                hx += xk * w2s[k * 32 + cp];
                hy += xk * w2s[k * 32 + cp + 1];
            }
            float ps = hx * avs2[cp] + hy * avs2[cp + 1];
            float pd = hx * avd2[cp] + hy * avd2[cp + 1];
#pragma unroll
            for (int off = 1; off < 16; off <<= 1) {
                ps += __shfl_xor(ps, off);
                pd += __shfl_xor(pd, off);
            }
            if (lane == 0) { as2[gn] = ps; ad2[gn] = pd; }
            if (lane < 16)
                *(__half2*)(hout + ((size_t)gn << 5) + cp) = __floats2half2_rn(hx, hy);
        }
    }
}

// ---------------- launch ----------------

extern "C" void kernel_launch(void* const* d_in, const int* in_sizes, int n_in,
                              void* d_out, int out_size, void* d_ws, size_t ws_size,
                              hipStream_t stream) {
    const int* x_ids = (const int*)d_in[0];
    const float* x_feat = (const float*)d_in[1];
    const int* src = (const int*)d_in[2];
    const int* dst = (const int*)d_in[3];
    const float* eattr = (const float*)d_in[4];
    const float* emb = (const float*)d_in[5];
    const float* W1 = (const float*)d_in[6];
    const float* a_s1 = (const float*)d_in[7];
    const float* a_d1 = (const float*)d_in[8];
    const float* We1 = (const float*)d_in[9];
    const float* a_e1 = (const float*)d_in[10];
    const float* b1 = (const float*)d_in[11];
    const float* W2 = (const float*)d_in[12];
    const float* a_s2 = (const float*)d_in[13];
    const float* a_d2 = (const float*)d_in[14];
    const float* We2 = (const float*)d_in[15];
    const float* a_e2 = (const float*)d_in[16];
    const float* b2 = (const float*)d_in[17];
    const float* lin_w = (const float*)d_in[18];
    const float* lin_b = (const float*)d_in[19];

    char* p = (char*)d_ws;
    auto alloc = [&](size_t bytes) {
        void* r = (void*)p;
        p += (bytes + 255) & ~(size_t)255;
        return r;
    };
    int* cnt = (int*)alloc(NBK * 4);
    float* asb1 = (float*)alloc(NN * 4);
    float* adb1 = (float*)alloc(NN * 4);
    float* asb2 = (float*)alloc(NN * 4);
    float* adb2 = (float*)alloc(NN * 4);
    __half* h1 = (__half*)alloc((size_t)NN * 32 * 2);    // 6.4 MB fp16
    __half* h2 = (__half*)alloc((size_t)NN * 32 * 2);    // 6.4 MB fp16
    int2* stage = (int2*)alloc((size_t)NBK * CAP * 8);   // 28.4 MB, lives thru both layers
    (void)ws_size; (void)in_sizes; (void)n_in; (void)out_size;

    hipMemsetAsync(cnt, 0, NBK * 4, stream);

    k_fat<<<NBB + NBT, 256, 0, stream>>>(src, dst, eattr, cnt, stage,
                                         x_ids, x_feat, emb, W1, a_s1, a_d1,
                                         h1, asb1, adb1);
    k_agg<false><<<NBK * 4, 256, 0, stream>>>(cnt, stage, h1, asb1, adb1,
                                              We1, a_e1, b1,
                                              W2, a_s2, a_d2, h2, asb2, adb2,
                                              nullptr, nullptr, nullptr);
    k_agg<true><<<NBK * 4, 256, 0, stream>>>(cnt, stage, h2, asb2, adb2,
                                             We2, a_e2, b2,
                                             nullptr, nullptr, nullptr,
                                             nullptr, nullptr, nullptr,
                                             lin_w, lin_b, (float*)d_out);
}